// Round 16
// baseline (392.489 us; speedup 1.0000x reference)
//
#include <hip/hip_runtime.h>
#include <hip/hip_cooperative_groups.h>

namespace cg = cooperative_groups;

#define B_    2
#define L_    1024
#define D_    1024
#define DIN_  2048
#define S_    16
#define R_    64
#define NTOK  (B_ * L_)   // 2048
#define NCH   32          // chunks along L
#define LC    (L_ / NCH)  // 32 steps per chunk

typedef unsigned short u16;
typedef short bf16x8 __attribute__((ext_vector_type(8)));
typedef float f32x4  __attribute__((ext_vector_type(4)));

__device__ __forceinline__ u16 f2bf(float f) {
    union { float f; unsigned u; } v; v.f = f;
    return (u16)((v.u + 0x7FFFu + ((v.u >> 16) & 1u)) >> 16);
}
__device__ __forceinline__ float bf2f(u16 b) {
    union { unsigned u; float f; } v; v.u = (unsigned)b << 16;
    return v.f;
}

// ---------------------------------------------------------------------------
// Fused prep: rmsnorm (blocks 0..2047) + all 4 weight transposes (rest).
__device__ __forceinline__ void transp_tile(
    const float* __restrict__ src, u16* __restrict__ dst,
    int R, int Csrc, int cx, int cy, int tx, int ty) {
    __shared__ float tile[32][33];
    int c0 = cx * 32, r0 = cy * 32;
#pragma unroll
    for (int i = 0; i < 32; i += 8)
        tile[ty + i][tx] = (c0 + tx < Csrc)
            ? src[(size_t)(r0 + ty + i) * Csrc + c0 + tx] : 0.f;
    __syncthreads();
#pragma unroll
    for (int i = 0; i < 32; i += 8)
        dst[(size_t)(c0 + ty + i) * R + r0 + tx] = f2bf(tile[tx][ty + i]);
}

__global__ __launch_bounds__(256) void prep_kernel(
    const float* __restrict__ x, const float* __restrict__ nw, u16* __restrict__ xn,
    const float* __restrict__ W_in,  u16* __restrict__ WinT,
    const float* __restrict__ W_out, u16* __restrict__ WoutT,
    const float* __restrict__ W_x,   u16* __restrict__ WxT,
    const float* __restrict__ W_dt,  u16* __restrict__ WdtT) {
    int bid = blockIdx.x;
    if (bid < NTOK) {                 // RMSNorm row
        int row = bid;
        const float4 v = ((const float4*)(x + (size_t)row * D_))[threadIdx.x];
        float ss = v.x * v.x + v.y * v.y + v.z * v.z + v.w * v.w;
#pragma unroll
        for (int o = 32; o > 0; o >>= 1) ss += __shfl_down(ss, o);
        __shared__ float red[4];
        if ((threadIdx.x & 63) == 0) red[threadIdx.x >> 6] = ss;
        __syncthreads();
        float tot = red[0] + red[1] + red[2] + red[3];
        float sc = rsqrtf(tot * (1.f / (float)D_) + 1e-5f);
        const float4 wv = ((const float4*)nw)[threadIdx.x];
        ushort4 o;
        o.x = f2bf(v.x * sc * wv.x);
        o.y = f2bf(v.y * sc * wv.y);
        o.z = f2bf(v.z * sc * wv.z);
        o.w = f2bf(v.w * sc * wv.w);
        ((ushort4*)(xn + (size_t)row * D_))[threadIdx.x] = o;
        return;
    }
    int b2 = bid - NTOK;
    int tx = threadIdx.x & 31, ty = threadIdx.x >> 5;
    if (b2 < 4096) {                  // W_in [1024,4096] -> [4096,1024]
        transp_tile(W_in, WinT, D_, 2 * DIN_, b2 % 128, b2 / 128, tx, ty);
    } else if (b2 < 6144) {           // W_out [2048,1024] -> [1024,2048]
        int b = b2 - 4096;
        transp_tile(W_out, WoutT, DIN_, D_, b % 32, b / 32, tx, ty);
    } else if (b2 < 6400) {           // W_x [2048,96] -> [128,2048] (pad 0)
        int b = b2 - 6144;
        transp_tile(W_x, WxT, DIN_, 96, b % 4, b / 4, tx, ty);
    } else {                          // W_dt [64,2048] -> [2048,64]
        int b = b2 - 6400;
        transp_tile(W_dt, WdtT, R_, DIN_, b % 64, b / 64, tx, ty);
    }
}

// ---------------------------------------------------------------------------
// bf16 MFMA GEMM: C[M,N] = A[M,K_tot] * Bt[N,K_tot]^T, f32 accumulate.
// 64x128 tile, 512 threads (8 waves, 2x4): per-wave 32x32 out (FM=FN=2),
// 4 MFMA/K-step. 1024-block grids resident at 4 blocks x 512 thr =
// 32 waves/CU (full wave occupancy). LDS 24KB 2-buffer. VGPR held via
// __launch_bounds__(512,8). 2D L2 raster per XCD (CX).
// mode 0: store f32/bf16 as given; 1: softplus(acc+aux[col]);
// 2: +aux[row*ldc+col]; 3: split-K partial at offset bz*M*N (bf16).
#define BK 32
template<int BM, int BN, int CX>
__global__ __launch_bounds__(512, 8) void gemm_bf16(
    const u16* __restrict__ A, int lda,
    const u16* __restrict__ Bt, int ldb,
    float* __restrict__ C, u16* __restrict__ Cbf, int ldc,
    const float* __restrict__ aux,
    int M, int N, int K, int mode) {
    constexpr int WROWS = BM / 32;          // 2 for 64
    constexpr int WCOLS = BN / 32;          // 4 for 128
    static_assert(WROWS * WCOLS == 8, "8 waves");
    constexpr int FM = 2;
    constexpr int FN = 2;
    constexpr int ABYTES = BM * BK * 2;     // 4096
    constexpr int BBYTES = BN * BK * 2;     // 8192
    __shared__ __align__(16) u16 As[2][BM * BK];
    __shared__ __align__(16) u16 Bs[2][BN * BK];
    const int t = threadIdx.x;
    const int w = t >> 6;                   // 0..7
    const int l = t & 63;
    const int lr = l & 15;
    const int kg = l >> 4;
    const int wm = (w / WCOLS) * 32;
    const int wn = (w % WCOLS) * 32;

    // 2D XCD raster (bijective; hardware round-robins h across XCDs).
    const int GX = gridDim.x, GY = gridDim.y;
    int h = blockIdx.x + GX * (blockIdx.y + GY * blockIdx.z);
    int xcd = h & 7, pos = h >> 3;
    int ncx = GX / CX;
    int chunk = (GX * GY * gridDim.z) >> 3;
    int rpc = chunk / CX;                 // rows per chunk
    int bx = (xcd % ncx) * CX + pos % CX;
    int r  = (xcd / ncx) * rpc + pos / CX;
    int by = r % GY;
    int bz = r / GY;

    const int row0 = by * BM;
    const int col0 = bx * BN;
    const int kbase = bz * K;

    auto stage = [&](int buf, int k0) {
        if (t < ABYTES / 16) {
            int off = t * 16;
            int grow = off >> 6;
            int sw = ((off >> 4) & 3) ^ ((grow >> 1) & 3);
            const u16* ga = A + (size_t)(row0 + grow) * lda + k0 + sw * 8;
            __builtin_amdgcn_global_load_lds(
                (const __attribute__((address_space(1))) unsigned int*)(const void*)ga,
                (__attribute__((address_space(3))) unsigned int*)(void*)&As[buf][off >> 1],
                16, 0, 0);
        }
        if (t < BBYTES / 16) {
            int off = t * 16;
            int grow = off >> 6;
            int sw = ((off >> 4) & 3) ^ ((grow >> 1) & 3);
            const u16* gb = Bt + (size_t)(col0 + grow) * ldb + k0 + sw * 8;
            __builtin_amdgcn_global_load_lds(
                (const __attribute__((address_space(1))) unsigned int*)(const void*)gb,
                (__attribute__((address_space(3))) unsigned int*)(void*)&Bs[buf][off >> 1],
                16, 0, 0);
        }
    };

    f32x4 acc[FM][FN];
#pragma unroll
    for (int i = 0; i < FM; ++i)
#pragma unroll
        for (int j = 0; j < FN; ++j) acc[i][j] = (f32x4){0.f, 0.f, 0.f, 0.f};

    const int nt = K / BK;
    stage(0, kbase);
    asm volatile("s_waitcnt vmcnt(0)" ::: "memory");
    __builtin_amdgcn_s_barrier();
    asm volatile("" ::: "memory");

    int cur = 0;
    for (int tt = 0; tt < nt; ++tt) {
        if (tt + 1 < nt) stage(cur ^ 1, kbase + (tt + 1) * BK);
        bf16x8 af[FM], bfr[FN];
#pragma unroll
        for (int mt = 0; mt < FM; ++mt) {
            int ar = wm + mt * 16 + lr;
            af[mt] = *(const bf16x8*)&As[cur][ar * 32 + (kg ^ ((ar >> 1) & 3)) * 8];
        }
#pragma unroll
        for (int nt2 = 0; nt2 < FN; ++nt2) {
            int br = wn + nt2 * 16 + lr;
            bfr[nt2] = *(const bf16x8*)&Bs[cur][br * 32 + (kg ^ ((br >> 1) & 3)) * 8];
        }
        __builtin_amdgcn_s_setprio(1);
#pragma unroll
        for (int mt = 0; mt < FM; ++mt)
#pragma unroll
            for (int nt2 = 0; nt2 < FN; ++nt2)
                acc[mt][nt2] = __builtin_amdgcn_mfma_f32_16x16x32_bf16(
                    af[mt], bfr[nt2], acc[mt][nt2], 0, 0, 0);
        __builtin_amdgcn_s_setprio(0);
        if (tt + 1 < nt) {
            asm volatile("s_waitcnt vmcnt(0)" ::: "memory");
            __builtin_amdgcn_s_barrier();
            asm volatile("" ::: "memory");
        }
        cur ^= 1;
    }

    size_t pbase = (mode == 3) ? (size_t)bz * M * N : 0;
#pragma unroll
    for (int mt = 0; mt < FM; ++mt) {
#pragma unroll
        for (int nt2 = 0; nt2 < FN; ++nt2) {
#pragma unroll
            for (int r2 = 0; r2 < 4; ++r2) {
                int row = row0 + wm + mt * 16 + kg * 4 + r2;
                int col = col0 + wn + nt2 * 16 + lr;
                float v = acc[mt][nt2][r2];
                if (mode == 1) { v += aux[col]; v = (v > 20.f) ? v : log1pf(__expf(v)); }
                else if (mode == 2) { v += aux[(size_t)row * ldc + col]; }
                if (C)   C[pbase + (size_t)row * ldc + col] = v;
                if (Cbf) Cbf[pbase + (size_t)row * ldc + col] = f2bf(v);
            }
        }
    }
}

// ---------------------------------------------------------------------------
// Split-K reduction for wx GEMM (bf16 partials): xdb = sum (bf16 only).
__global__ __launch_bounds__(256) void reduce_wx_kernel(
    const u16* __restrict__ part, u16* __restrict__ xdb) {
    int i = blockIdx.x * 256 + threadIdx.x;   // over NTOK*128/4
    float sx = 0.f, sy = 0.f, sz = 0.f, sw = 0.f;
#pragma unroll
    for (int k = 0; k < 16; ++k) {
        ushort4 v = ((const ushort4*)(part + (size_t)k * NTOK * 128))[i];
        sx += bf2f(v.x); sy += bf2f(v.y); sz += bf2f(v.z); sw += bf2f(v.w);
    }
    ushort4 o; o.x = f2bf(sx); o.y = f2bf(sy); o.z = f2bf(sz); o.w = f2bf(sw);
    ((ushort4*)xdb)[i] = o;
}

// Split-K reduction for out GEMM (bf16 partials): out = sum + x (residual).
__global__ __launch_bounds__(256) void reduce_out_kernel(
    const u16* __restrict__ part, const float* __restrict__ x, float* __restrict__ out) {
    int i = blockIdx.x * 256 + threadIdx.x;   // over NTOK*D/4
    float sx = 0.f, sy = 0.f, sz = 0.f, sw = 0.f;
#pragma unroll
    for (int k = 0; k < 4; ++k) {
        ushort4 v = ((const ushort4*)(part + (size_t)k * NTOK * D_))[i];
        sx += bf2f(v.x); sy += bf2f(v.y); sz += bf2f(v.z); sw += bf2f(v.w);
    }
    float4 xv = ((const float4*)x)[i];
    float4 s = {sx + xv.x, sy + xv.y, sz + xv.z, sw + xv.w};
    ((float4*)out)[i] = s;
}

// ---------------------------------------------------------------------------
// Causal depthwise conv (K=4) + bias + SiLU, sliding window (bf16 in/out).
__global__ __launch_bounds__(256) void conv_silu_kernel(
    const u16* __restrict__ xzb, const float* __restrict__ cw,
    const float* __restrict__ cb, u16* __restrict__ xcb) {
    size_t idx = (size_t)blockIdx.x * 256 + threadIdx.x;   // over NTOK*DIN/4
    int c = (int)(idx & (DIN_ - 1));
    int g = (int)(idx >> 11);          // group of 4 rows
    int bl0 = g * 4;
    int l0 = bl0 & (L_ - 1);
    const float4 w = ((const float4*)cw)[c];
    float bias = cb[c];
    float v[7];
#pragma unroll
    for (int k = 0; k < 7; ++k) {
        int off = k - 3;
        v[k] = (l0 + off >= 0) ? bf2f(xzb[(size_t)(bl0 + off) * 4096 + c]) : 0.f;
    }
#pragma unroll
    for (int j = 0; j < 4; ++j) {
        float acc = bias + v[j] * w.x + v[j + 1] * w.y + v[j + 2] * w.z + v[j + 3] * w.w;
        float s = acc / (1.f + __expf(-acc));
        xcb[(size_t)(bl0 + j) * DIN_ + c] = f2bf(s);
    }
}

// ---------------------------------------------------------------------------
// Helper: load 16 bf16 B (or C) values from an xdb row (broadcast).
__device__ __forceinline__ void load16(const u16* p, float* dst) {
    bf16x8 v0 = *(const bf16x8*)p;
    bf16x8 v1 = *(const bf16x8*)(p + 8);
#pragma unroll
    for (int j = 0; j < 8; ++j) {
        dst[j]     = bf2f((u16)v0[j]);
        dst[8 + j] = bf2f((u16)v1[j]);
    }
}

// ---------------------------------------------------------------------------
// COOPERATIVE fused scan: one dispatch replaces chunk/combine/final.
// Grid (8,32,2) = 512 blocks x 256 thr (2 blocks/CU co-resident).
// Phase 1: per-chunk scan, P/H bf16 -> global (L2-hot).  grid.sync()
// Phase 2: first 65536 threads do the NCH-chunk combine -> h0 f32.  grid.sync()
// Phase 3: replay from h0, state-reduce, skip+gate -> yg bf16.
// Math identical to the round-15 trio (same layouts, same precision).
__global__ __launch_bounds__(256) void scan_coop_kernel(
    const u16* __restrict__ dtq, const u16* __restrict__ xcb,
    const u16* __restrict__ xdb, const float* __restrict__ A_log,
    u16* __restrict__ Pbuf, u16* __restrict__ Hbuf, float* __restrict__ h0,
    const float* __restrict__ Dskip, const u16* __restrict__ xzb,
    u16* __restrict__ yg) {
    cg::grid_group grid = cg::this_grid();
    const int din = blockIdx.x * 256 + threadIdx.x;
    const int c = blockIdx.y, b = blockIdx.z;

    float a[S_], h[S_];
#pragma unroll
    for (int q = 0; q < 4; ++q) {
        float4 av = ((const float4*)(A_log + (size_t)din * S_))[q];
        a[q * 4 + 0] = -__expf(av.x); a[q * 4 + 1] = -__expf(av.y);
        a[q * 4 + 2] = -__expf(av.z); a[q * 4 + 3] = -__expf(av.w);
    }
#pragma unroll
    for (int s = 0; s < S_; ++s) h[s] = 0.f;
    float sdt = 0.f;
    size_t rbase = (size_t)b * L_ + (size_t)c * LC;

    // Phase 1: local chunk scan.
#pragma unroll 2
    for (int i = 0; i < LC; ++i) {
        size_t row = rbase + i;
        float dtv = bf2f(dtq[row * DIN_ + din]);
        float xcv = bf2f(xcb[row * DIN_ + din]);
        float du = dtv * xcv;
        sdt += dtv;
        float Bv[S_];
        load16(xdb + row * 128 + 64, Bv);
#pragma unroll
        for (int s = 0; s < S_; ++s) {
            float dA = __expf(dtv * a[s]);
            h[s] = h[s] * dA + du * Bv[s];
        }
    }
    size_t obase = ((size_t)(b * NCH + c) * DIN_ + din) * S_;
    {
        bf16x8 pv0, pv1, hv0, hv1;
#pragma unroll
        for (int s = 0; s < 8; ++s) {
            pv0[s] = (short)f2bf(__expf(a[s] * sdt));
            pv1[s] = (short)f2bf(__expf(a[8 + s] * sdt));
            hv0[s] = (short)f2bf(h[s]);
            hv1[s] = (short)f2bf(h[8 + s]);
        }
        *(bf16x8*)&Pbuf[obase] = pv0;
        *(bf16x8*)&Pbuf[obase + 8] = pv1;
        *(bf16x8*)&Hbuf[obase] = hv0;
        *(bf16x8*)&Hbuf[obase + 8] = hv1;
    }
    __threadfence();
    grid.sync();

    // Phase 2: combine (first 65536 global threads).
    {
        int bid = blockIdx.x + gridDim.x * (blockIdx.y + gridDim.y * blockIdx.z);
        int gtid = bid * 256 + threadIdx.x;
        if (gtid < B_ * DIN_ * S_) {
            int ds = gtid & (DIN_ * S_ - 1);
            int b2 = gtid >> 15;
            float hh = 0.f;
#pragma unroll
            for (int cc = 0; cc < NCH; ++cc) {
                size_t idx = ((size_t)(b2 * NCH + cc) * DIN_ * S_) + ds;
                h0[idx] = hh;
                hh = bf2f(Hbuf[idx]) + bf2f(Pbuf[idx]) * hh;
            }
        }
    }
    __threadfence();
    grid.sync();

    // Phase 3: replay from h0 with output.
#pragma unroll
    for (int q = 0; q < 4; ++q) {
        float4 hv = ((const float4*)(h0 + obase))[q];
        h[q * 4 + 0] = hv.x; h[q * 4 + 1] = hv.y; h[q * 4 + 2] = hv.z; h[q * 4 + 3] = hv.w;
    }
    float dsk = Dskip[din];
#pragma unroll 2
    for (int i = 0; i < LC; ++i) {
        size_t row = rbase + i;
        float dtv = bf2f(dtq[row * DIN_ + din]);
        float xcv = bf2f(xcb[row * DIN_ + din]);
        float du = dtv * xcv;
        float Bv[S_], Cv[S_];
        load16(xdb + row * 128 + 64, Bv);
        load16(xdb + row * 128 + 80, Cv);
        float py = 0.f;
#pragma unroll
        for (int s = 0; s < S_; ++s) {
            float dA = __expf(dtv * a[s]);
            h[s] = h[s] * dA + du * Bv[s];
            py += h[s] * Cv[s];
        }
        float zv = bf2f(xzb[row * 4096 + DIN_ + din]);
        float y = (py + dsk * xcv) * (zv / (1.f + __expf(-zv)));
        yg[row * DIN_ + din] = f2bf(y);
    }
}

// ---------------------------------------------------------------------------
extern "C" void kernel_launch(void* const* d_in, const int* in_sizes, int n_in,
                              void* d_out, int out_size, void* d_ws, size_t ws_size,
                              hipStream_t stream) {
    const float* x      = (const float*)d_in[0];
    const float* norm_w = (const float*)d_in[1];
    const float* W_in   = (const float*)d_in[2];
    const float* conv_w = (const float*)d_in[3];
    const float* conv_b = (const float*)d_in[4];
    const float* W_x    = (const float*)d_in[5];
    const float* W_dt   = (const float*)d_in[6];
    const float* b_dt   = (const float*)d_in[7];
    const float* A_log  = (const float*)d_in[8];
    const float* D_skip = (const float*)d_in[9];
    const float* W_out  = (const float*)d_in[10];
    float* out = (float*)d_out;

    char* p = (char*)d_ws;
    auto alloc = [&](size_t bytes) {
        char* r = p;
        p += (bytes + 255) & ~(size_t)255;
        return r;
    };
    u16*   xn      = (u16*)alloc((size_t)NTOK * D_ * 2);
    u16*   WinT    = (u16*)alloc((size_t)2 * DIN_ * D_ * 2);
    u16*   WoutT   = (u16*)alloc((size_t)D_ * DIN_ * 2);
    u16*   WxT     = (u16*)alloc((size_t)128 * DIN_ * 2);
    u16*   WdtT   = (u16*)alloc((size_t)DIN_ * R_ * 2);
    u16*   xzb     = (u16*)alloc((size_t)NTOK * 2 * DIN_ * 2);    // 16MB bf16
    u16*   xcb     = (u16*)alloc((size_t)NTOK * DIN_ * 2);
    u16*   xdb     = (u16*)alloc((size_t)NTOK * 128 * 2);
    u16*   dtq     = (u16*)alloc((size_t)NTOK * DIN_ * 2);        // 8MB bf16
    u16*   yg      = (u16*)alloc((size_t)NTOK * DIN_ * 2);
    u16*   Pbuf    = (u16*)alloc((size_t)B_ * NCH * DIN_ * S_ * 2);   // 4MB
    u16*   Hbuf    = (u16*)alloc((size_t)B_ * NCH * DIN_ * S_ * 2);   // 4MB
    float* h0buf   = (float*)alloc((size_t)B_ * NCH * DIN_ * S_ * 4); // 8MB
    u16*   part_out = (u16*)alloc((size_t)4 * NTOK * D_ * 2);     // 16MB bf16
    // wx partials [16][2048][128] bf16 (8MB) alias part_out (disjoint lifetimes).
    u16*   part_wx  = part_out;

    // prep: rmsnorm (2048 blocks) + 4 transposes (6528 blocks)
    prep_kernel<<<NTOK + 6528, 256, 0, stream>>>(
        x, norm_w, xn, W_in, WinT, W_out, WoutT, W_x, WxT, W_dt, WdtT);

    // xz = xn @ W_in -> bf16 [2048, 4096]  (32x32 = 1024 blocks x 512thr; CX=8)
    gemm_bf16<64, 128, 8><<<dim3(2 * DIN_ / 128, NTOK / 64), 512, 0, stream>>>(
        xn, D_, WinT, D_, nullptr, xzb, 2 * DIN_, nullptr, NTOK, 2 * DIN_, D_, 0);
    // conv + silu -> xcb (bf16), 4 L-positions per thread
    conv_silu_kernel<<<(NTOK * DIN_ / 4) / 256, 256, 0, stream>>>(xzb, conv_w, conv_b, xcb);
    // xd = xc @ W_x (padded to N=128), split-K=16, bf16 partials (512 blocks)
    gemm_bf16<64, 128, 1><<<dim3(1, NTOK / 64, 16), 512, 0, stream>>>(
        xcb, DIN_, WxT, DIN_, nullptr, part_wx, 128, nullptr, NTOK, 128, DIN_ / 16, 3);
    reduce_wx_kernel<<<(NTOK * 128 / 4) / 256, 256, 0, stream>>>(part_wx, xdb);
    // dt = softplus(xd[:, :64] @ W_dt + b_dt) -> bf16  (16x32 = 512 blocks)
    gemm_bf16<64, 128, 8><<<dim3(DIN_ / 128, NTOK / 64), 512, 0, stream>>>(
        xdb, 128, WdtT, R_, nullptr, dtq, DIN_, b_dt, NTOK, DIN_, R_, 1);
    // cooperative fused scan + gate -> yg (bf16): single dispatch
    {
        void* kargs[] = {
            (void*)&dtq, (void*)&xcb, (void*)&xdb, (void*)&A_log,
            (void*)&Pbuf, (void*)&Hbuf, (void*)&h0buf,
            (void*)&D_skip, (void*)&xzb, (void*)&yg
        };
        hipLaunchCooperativeKernel((void*)scan_coop_kernel,
                                   dim3(DIN_ / 256, NCH, B_), dim3(256),
                                   kargs, 0, stream);
    }
    // out = x + yg @ W_out, split-K=4, bf16 partials  (8x32x4 = 1024 blocks; CX=8)
    gemm_bf16<64, 128, 8><<<dim3(D_ / 128, NTOK / 64, 4), 512, 0, stream>>>(
        yg, DIN_, WoutT, DIN_, nullptr, part_out, D_, nullptr, NTOK, D_, DIN_ / 4, 3);
    reduce_out_kernel<<<(NTOK * D_ / 4) / 256, 256, 0, stream>>>(part_out, x, out);
}

// Round 17
// 154.617 us; speedup vs baseline: 2.5385x; 2.5385x over previous
//
#include <hip/hip_runtime.h>

#define B_    2
#define L_    1024
#define D_    1024
#define DIN_  2048
#define S_    16
#define R_    64
#define NTOK  (B_ * L_)   // 2048
#define NCH   32          // chunks along L
#define LC    (L_ / NCH)  // 32 steps per chunk

typedef unsigned short u16;
typedef unsigned int u32;
typedef short bf16x8 __attribute__((ext_vector_type(8)));
typedef float f32x4  __attribute__((ext_vector_type(4)));

__device__ __forceinline__ u16 f2bf(float f) {
    union { float f; unsigned u; } v; v.f = f;
    return (u16)((v.u + 0x7FFFu + ((v.u >> 16) & 1u)) >> 16);
}
__device__ __forceinline__ float bf2f(u16 b) {
    union { unsigned u; float f; } v; v.u = (unsigned)b << 16;
    return v.f;
}

// ---------------------------------------------------------------------------
// Fused prep: rmsnorm (blocks 0..2047) + all 4 weight transposes (rest).
__device__ __forceinline__ void transp_tile(
    const float* __restrict__ src, u16* __restrict__ dst,
    int R, int Csrc, int cx, int cy, int tx, int ty) {
    __shared__ float tile[32][33];
    int c0 = cx * 32, r0 = cy * 32;
#pragma unroll
    for (int i = 0; i < 32; i += 8)
        tile[ty + i][tx] = (c0 + tx < Csrc)
            ? src[(size_t)(r0 + ty + i) * Csrc + c0 + tx] : 0.f;
    __syncthreads();
#pragma unroll
    for (int i = 0; i < 32; i += 8)
        dst[(size_t)(c0 + ty + i) * R + r0 + tx] = f2bf(tile[tx][ty + i]);
}

__global__ __launch_bounds__(256) void prep_kernel(
    const float* __restrict__ x, const float* __restrict__ nw, u16* __restrict__ xn,
    const float* __restrict__ W_in,  u16* __restrict__ WinT,
    const float* __restrict__ W_out, u16* __restrict__ WoutT,
    const float* __restrict__ W_x,   u16* __restrict__ WxT,
    const float* __restrict__ W_dt,  u16* __restrict__ WdtT) {
    int bid = blockIdx.x;
    if (bid < NTOK) {                 // RMSNorm row
        int row = bid;
        const float4 v = ((const float4*)(x + (size_t)row * D_))[threadIdx.x];
        float ss = v.x * v.x + v.y * v.y + v.z * v.z + v.w * v.w;
#pragma unroll
        for (int o = 32; o > 0; o >>= 1) ss += __shfl_down(ss, o);
        __shared__ float red[4];
        if ((threadIdx.x & 63) == 0) red[threadIdx.x >> 6] = ss;
        __syncthreads();
        float tot = red[0] + red[1] + red[2] + red[3];
        float sc = rsqrtf(tot * (1.f / (float)D_) + 1e-5f);
        const float4 wv = ((const float4*)nw)[threadIdx.x];
        ushort4 o;
        o.x = f2bf(v.x * sc * wv.x);
        o.y = f2bf(v.y * sc * wv.y);
        o.z = f2bf(v.z * sc * wv.z);
        o.w = f2bf(v.w * sc * wv.w);
        ((ushort4*)(xn + (size_t)row * D_))[threadIdx.x] = o;
        return;
    }
    int b2 = bid - NTOK;
    int tx = threadIdx.x & 31, ty = threadIdx.x >> 5;
    if (b2 < 4096) {                  // W_in [1024,4096] -> [4096,1024]
        transp_tile(W_in, WinT, D_, 2 * DIN_, b2 % 128, b2 / 128, tx, ty);
    } else if (b2 < 6144) {           // W_out [2048,1024] -> [1024,2048]
        int b = b2 - 4096;
        transp_tile(W_out, WoutT, DIN_, D_, b % 32, b / 32, tx, ty);
    } else if (b2 < 6400) {           // W_x [2048,96] -> [128,2048] (pad 0)
        int b = b2 - 6144;
        transp_tile(W_x, WxT, DIN_, 96, b % 4, b / 4, tx, ty);
    } else {                          // W_dt [64,2048] -> [2048,64]
        int b = b2 - 6400;
        transp_tile(W_dt, WdtT, R_, DIN_, b % 64, b / 64, tx, ty);
    }
}

// ---------------------------------------------------------------------------
// bf16 MFMA GEMM: C[M,N] = A[M,K_tot] * Bt[N,K_tot]^T, f32 accumulate.
// 64x128 tile, 512 threads (8 waves, 2x4): per-wave 32x32 out (FM=FN=2),
// 4 MFMA/K-step. 1024-block grids resident at 4 blocks x 512 thr =
// 32 waves/CU (full wave occupancy). LDS 24KB 2-buffer. VGPR held via
// __launch_bounds__(512,8). 2D L2 raster per XCD (CX).
// mode 0: store f32/bf16 as given; 1: softplus(acc+aux[col]);
// 2: +aux[row*ldc+col]; 3: split-K partial at offset bz*M*N (bf16).
#define BK 32
template<int BM, int BN, int CX>
__global__ __launch_bounds__(512, 8) void gemm_bf16(
    const u16* __restrict__ A, int lda,
    const u16* __restrict__ Bt, int ldb,
    float* __restrict__ C, u16* __restrict__ Cbf, int ldc,
    const float* __restrict__ aux,
    int M, int N, int K, int mode) {
    constexpr int WROWS = BM / 32;          // 2 for 64
    constexpr int WCOLS = BN / 32;          // 4 for 128
    static_assert(WROWS * WCOLS == 8, "8 waves");
    constexpr int FM = 2;
    constexpr int FN = 2;
    constexpr int ABYTES = BM * BK * 2;     // 4096
    constexpr int BBYTES = BN * BK * 2;     // 8192
    __shared__ __align__(16) u16 As[2][BM * BK];
    __shared__ __align__(16) u16 Bs[2][BN * BK];
    const int t = threadIdx.x;
    const int w = t >> 6;                   // 0..7
    const int l = t & 63;
    const int lr = l & 15;
    const int kg = l >> 4;
    const int wm = (w / WCOLS) * 32;
    const int wn = (w % WCOLS) * 32;

    // 2D XCD raster (bijective; hardware round-robins h across XCDs).
    const int GX = gridDim.x, GY = gridDim.y;
    int h = blockIdx.x + GX * (blockIdx.y + GY * blockIdx.z);
    int xcd = h & 7, pos = h >> 3;
    int ncx = GX / CX;
    int chunk = (GX * GY * gridDim.z) >> 3;
    int rpc = chunk / CX;                 // rows per chunk
    int bx = (xcd % ncx) * CX + pos % CX;
    int r  = (xcd / ncx) * rpc + pos / CX;
    int by = r % GY;
    int bz = r / GY;

    const int row0 = by * BM;
    const int col0 = bx * BN;
    const int kbase = bz * K;

    auto stage = [&](int buf, int k0) {
        if (t < ABYTES / 16) {
            int off = t * 16;
            int grow = off >> 6;
            int sw = ((off >> 4) & 3) ^ ((grow >> 1) & 3);
            const u16* ga = A + (size_t)(row0 + grow) * lda + k0 + sw * 8;
            __builtin_amdgcn_global_load_lds(
                (const __attribute__((address_space(1))) unsigned int*)(const void*)ga,
                (__attribute__((address_space(3))) unsigned int*)(void*)&As[buf][off >> 1],
                16, 0, 0);
        }
        if (t < BBYTES / 16) {
            int off = t * 16;
            int grow = off >> 6;
            int sw = ((off >> 4) & 3) ^ ((grow >> 1) & 3);
            const u16* gb = Bt + (size_t)(col0 + grow) * ldb + k0 + sw * 8;
            __builtin_amdgcn_global_load_lds(
                (const __attribute__((address_space(1))) unsigned int*)(const void*)gb,
                (__attribute__((address_space(3))) unsigned int*)(void*)&Bs[buf][off >> 1],
                16, 0, 0);
        }
    };

    f32x4 acc[FM][FN];
#pragma unroll
    for (int i = 0; i < FM; ++i)
#pragma unroll
        for (int j = 0; j < FN; ++j) acc[i][j] = (f32x4){0.f, 0.f, 0.f, 0.f};

    const int nt = K / BK;
    stage(0, kbase);
    asm volatile("s_waitcnt vmcnt(0)" ::: "memory");
    __builtin_amdgcn_s_barrier();
    asm volatile("" ::: "memory");

    int cur = 0;
    for (int tt = 0; tt < nt; ++tt) {
        if (tt + 1 < nt) stage(cur ^ 1, kbase + (tt + 1) * BK);
        bf16x8 af[FM], bfr[FN];
#pragma unroll
        for (int mt = 0; mt < FM; ++mt) {
            int ar = wm + mt * 16 + lr;
            af[mt] = *(const bf16x8*)&As[cur][ar * 32 + (kg ^ ((ar >> 1) & 3)) * 8];
        }
#pragma unroll
        for (int nt2 = 0; nt2 < FN; ++nt2) {
            int br = wn + nt2 * 16 + lr;
            bfr[nt2] = *(const bf16x8*)&Bs[cur][br * 32 + (kg ^ ((br >> 1) & 3)) * 8];
        }
        __builtin_amdgcn_s_setprio(1);
#pragma unroll
        for (int mt = 0; mt < FM; ++mt)
#pragma unroll
            for (int nt2 = 0; nt2 < FN; ++nt2)
                acc[mt][nt2] = __builtin_amdgcn_mfma_f32_16x16x32_bf16(
                    af[mt], bfr[nt2], acc[mt][nt2], 0, 0, 0);
        __builtin_amdgcn_s_setprio(0);
        if (tt + 1 < nt) {
            asm volatile("s_waitcnt vmcnt(0)" ::: "memory");
            __builtin_amdgcn_s_barrier();
            asm volatile("" ::: "memory");
        }
        cur ^= 1;
    }

    size_t pbase = (mode == 3) ? (size_t)bz * M * N : 0;
#pragma unroll
    for (int mt = 0; mt < FM; ++mt) {
#pragma unroll
        for (int nt2 = 0; nt2 < FN; ++nt2) {
#pragma unroll
            for (int r2 = 0; r2 < 4; ++r2) {
                int row = row0 + wm + mt * 16 + kg * 4 + r2;
                int col = col0 + wn + nt2 * 16 + lr;
                float v = acc[mt][nt2][r2];
                if (mode == 1) { v += aux[col]; v = (v > 20.f) ? v : log1pf(__expf(v)); }
                else if (mode == 2) { v += aux[(size_t)row * ldc + col]; }
                if (C)   C[pbase + (size_t)row * ldc + col] = v;
                if (Cbf) Cbf[pbase + (size_t)row * ldc + col] = f2bf(v);
            }
        }
    }
}

// ---------------------------------------------------------------------------
// Split-K reduction for wx GEMM (bf16 partials): xdb = sum (bf16 only).
__global__ __launch_bounds__(256) void reduce_wx_kernel(
    const u16* __restrict__ part, u16* __restrict__ xdb) {
    int i = blockIdx.x * 256 + threadIdx.x;   // over NTOK*128/4
    float sx = 0.f, sy = 0.f, sz = 0.f, sw = 0.f;
#pragma unroll
    for (int k = 0; k < 16; ++k) {
        ushort4 v = ((const ushort4*)(part + (size_t)k * NTOK * 128))[i];
        sx += bf2f(v.x); sy += bf2f(v.y); sz += bf2f(v.z); sw += bf2f(v.w);
    }
    ushort4 o; o.x = f2bf(sx); o.y = f2bf(sy); o.z = f2bf(sz); o.w = f2bf(sw);
    ((ushort4*)xdb)[i] = o;
}

// Split-K reduction for out GEMM (bf16 partials): out = sum + x (residual).
__global__ __launch_bounds__(256) void reduce_out_kernel(
    const u16* __restrict__ part, const float* __restrict__ x, float* __restrict__ out) {
    int i = blockIdx.x * 256 + threadIdx.x;   // over NTOK*D/4
    float sx = 0.f, sy = 0.f, sz = 0.f, sw = 0.f;
#pragma unroll
    for (int k = 0; k < 4; ++k) {
        ushort4 v = ((const ushort4*)(part + (size_t)k * NTOK * D_))[i];
        sx += bf2f(v.x); sy += bf2f(v.y); sz += bf2f(v.z); sw += bf2f(v.w);
    }
    float4 xv = ((const float4*)x)[i];
    float4 s = {sx + xv.x, sy + xv.y, sz + xv.z, sw + xv.w};
    ((float4*)out)[i] = s;
}

// ---------------------------------------------------------------------------
// Causal depthwise conv (K=4) + bias + SiLU, sliding window, 2 channels per
// thread (u32 loads/stores): 7 u32 loads -> 4x2 outputs.
__global__ __launch_bounds__(256) void conv_silu_kernel(
    const u16* __restrict__ xzb, const float* __restrict__ cw,
    const float* __restrict__ cb, u16* __restrict__ xcb) {
    size_t idx = (size_t)blockIdx.x * 256 + threadIdx.x;   // over NTOK*DIN/8
    int cp = (int)(idx & (DIN_ / 2 - 1));   // channel pair
    int c = cp * 2;
    int g = (int)(idx >> 10);               // group of 4 rows
    int bl0 = g * 4;
    int l0 = bl0 & (L_ - 1);
    const float4 w0 = ((const float4*)cw)[c];
    const float4 w1 = ((const float4*)cw)[c + 1];
    float b0 = cb[c], b1 = cb[c + 1];
    float v0[7], v1[7];
#pragma unroll
    for (int k = 0; k < 7; ++k) {
        int off = k - 3;
        if (l0 + off >= 0) {
            u32 pk = *(const u32*)&xzb[(size_t)(bl0 + off) * 4096 + c];
            v0[k] = bf2f((u16)(pk & 0xFFFF));
            v1[k] = bf2f((u16)(pk >> 16));
        } else { v0[k] = 0.f; v1[k] = 0.f; }
    }
#pragma unroll
    for (int j = 0; j < 4; ++j) {
        float a0 = b0 + v0[j] * w0.x + v0[j + 1] * w0.y + v0[j + 2] * w0.z + v0[j + 3] * w0.w;
        float a1 = b1 + v1[j] * w1.x + v1[j + 1] * w1.y + v1[j + 2] * w1.z + v1[j + 3] * w1.w;
        float s0 = a0 / (1.f + __expf(-a0));
        float s1 = a1 / (1.f + __expf(-a1));
        u32 pk = (u32)f2bf(s0) | ((u32)f2bf(s1) << 16);
        *(u32*)&xcb[(size_t)(bl0 + j) * DIN_ + c] = pk;
    }
}

// ---------------------------------------------------------------------------
// Helper: load 16 bf16 B (or C) values from an xdb row (broadcast).
__device__ __forceinline__ void load16(const u16* p, float* dst) {
    bf16x8 v0 = *(const bf16x8*)p;
    bf16x8 v1 = *(const bf16x8*)(p + 8);
#pragma unroll
    for (int j = 0; j < 8; ++j) {
        dst[j]     = bf2f((u16)v0[j]);
        dst[8 + j] = bf2f((u16)v1[j]);
    }
}

// Chunked selective scan, din-in-lane layout (256 din/block: B/C reads are
// same-address broadcasts). States in registers. P/H stored bf16.
__global__ __launch_bounds__(256) void scan_chunk_kernel(
    const u16* __restrict__ dtq, const u16* __restrict__ xcb,
    const u16* __restrict__ xdb, const float* __restrict__ A_log,
    u16* __restrict__ Pout, u16* __restrict__ Hout) {
    int din = blockIdx.x * 256 + threadIdx.x;
    int c = blockIdx.y, b = blockIdx.z;
    float a[S_], h[S_];
#pragma unroll
    for (int q = 0; q < 4; ++q) {
        float4 av = ((const float4*)(A_log + (size_t)din * S_))[q];
        a[q * 4 + 0] = -__expf(av.x); a[q * 4 + 1] = -__expf(av.y);
        a[q * 4 + 2] = -__expf(av.z); a[q * 4 + 3] = -__expf(av.w);
    }
#pragma unroll
    for (int s = 0; s < S_; ++s) h[s] = 0.f;
    float sdt = 0.f;
    size_t rbase = (size_t)b * L_ + (size_t)c * LC;
#pragma unroll 2
    for (int i = 0; i < LC; ++i) {
        size_t row = rbase + i;
        float dtv = bf2f(dtq[row * DIN_ + din]);
        float xcv = bf2f(xcb[row * DIN_ + din]);
        float du = dtv * xcv;
        sdt += dtv;
        float Bv[S_];
        load16(xdb + row * 128 + 64, Bv);
#pragma unroll
        for (int s = 0; s < S_; ++s) {
            float dA = __expf(dtv * a[s]);
            h[s] = h[s] * dA + du * Bv[s];
        }
    }
    size_t obase = ((size_t)(b * NCH + c) * DIN_ + din) * S_;
    bf16x8 pv0, pv1, hv0, hv1;
#pragma unroll
    for (int s = 0; s < 8; ++s) {
        pv0[s] = (short)f2bf(__expf(a[s] * sdt));
        pv1[s] = (short)f2bf(__expf(a[8 + s] * sdt));
        hv0[s] = (short)f2bf(h[s]);
        hv1[s] = (short)f2bf(h[8 + s]);
    }
    *(bf16x8*)&Pout[obase] = pv0;
    *(bf16x8*)&Pout[obase + 8] = pv1;
    *(bf16x8*)&Hout[obase] = hv0;
    *(bf16x8*)&Hout[obase + 8] = hv1;
}

// Phase 2: exclusive scan over NCH chunks for each (b, din, s); h0 f32.
__global__ __launch_bounds__(256) void scan_combine_kernel(
    const u16* __restrict__ P, const u16* __restrict__ H,
    float* __restrict__ h0) {
    int tid = blockIdx.x * 256 + threadIdx.x;   // B * DIN * S = 65536
    int ds = tid & (DIN_ * S_ - 1);
    int b = tid >> 15;
    float h = 0.f;
#pragma unroll
    for (int c = 0; c < NCH; ++c) {
        size_t idx = ((size_t)(b * NCH + c) * DIN_ * S_) + ds;
        h0[idx] = h;
        h = bf2f(H[idx]) + bf2f(P[idx]) * h;
    }
}

// Phase 3: replay chunk from h0, per-thread state reduce, skip + gate, write bf16.
__global__ __launch_bounds__(256) void scan_final_kernel(
    const u16* __restrict__ dtq, const u16* __restrict__ xcb,
    const u16* __restrict__ xdb, const float* __restrict__ A_log,
    const float* __restrict__ h0, const float* __restrict__ Dskip,
    const u16* __restrict__ xzb, u16* __restrict__ yg) {
    int din = blockIdx.x * 256 + threadIdx.x;
    int c = blockIdx.y, b = blockIdx.z;
    float a[S_], h[S_];
#pragma unroll
    for (int q = 0; q < 4; ++q) {
        float4 av = ((const float4*)(A_log + (size_t)din * S_))[q];
        a[q * 4 + 0] = -__expf(av.x); a[q * 4 + 1] = -__expf(av.y);
        a[q * 4 + 2] = -__expf(av.z); a[q * 4 + 3] = -__expf(av.w);
    }
    size_t ibase = ((size_t)(b * NCH + c) * DIN_ + din) * S_;
#pragma unroll
    for (int q = 0; q < 4; ++q) {
        float4 hv = ((const float4*)(h0 + ibase))[q];
        h[q * 4 + 0] = hv.x; h[q * 4 + 1] = hv.y; h[q * 4 + 2] = hv.z; h[q * 4 + 3] = hv.w;
    }
    float dsk = Dskip[din];
    size_t rbase = (size_t)b * L_ + (size_t)c * LC;
#pragma unroll 2
    for (int i = 0; i < LC; ++i) {
        size_t row = rbase + i;
        float dtv = bf2f(dtq[row * DIN_ + din]);
        float xcv = bf2f(xcb[row * DIN_ + din]);
        float du = dtv * xcv;
        float Bv[S_], Cv[S_];
        load16(xdb + row * 128 + 64, Bv);
        load16(xdb + row * 128 + 80, Cv);
        float py = 0.f;
#pragma unroll
        for (int s = 0; s < S_; ++s) {
            float dA = __expf(dtv * a[s]);
            h[s] = h[s] * dA + du * Bv[s];
            py += h[s] * Cv[s];
        }
        float zv = bf2f(xzb[row * 4096 + DIN_ + din]);
        float y = (py + dsk * xcv) * (zv / (1.f + __expf(-zv)));
        yg[row * DIN_ + din] = f2bf(y);
    }
}

// ---------------------------------------------------------------------------
extern "C" void kernel_launch(void* const* d_in, const int* in_sizes, int n_in,
                              void* d_out, int out_size, void* d_ws, size_t ws_size,
                              hipStream_t stream) {
    const float* x      = (const float*)d_in[0];
    const float* norm_w = (const float*)d_in[1];
    const float* W_in   = (const float*)d_in[2];
    const float* conv_w = (const float*)d_in[3];
    const float* conv_b = (const float*)d_in[4];
    const float* W_x    = (const float*)d_in[5];
    const float* W_dt   = (const float*)d_in[6];
    const float* b_dt   = (const float*)d_in[7];
    const float* A_log  = (const float*)d_in[8];
    const float* D_skip = (const float*)d_in[9];
    const float* W_out  = (const float*)d_in[10];
    float* out = (float*)d_out;

    char* p = (char*)d_ws;
    auto alloc = [&](size_t bytes) {
        char* r = p;
        p += (bytes + 255) & ~(size_t)255;
        return r;
    };
    u16*   xn      = (u16*)alloc((size_t)NTOK * D_ * 2);
    u16*   WinT    = (u16*)alloc((size_t)2 * DIN_ * D_ * 2);
    u16*   WoutT   = (u16*)alloc((size_t)D_ * DIN_ * 2);
    u16*   WxT     = (u16*)alloc((size_t)128 * DIN_ * 2);
    u16*   WdtT    = (u16*)alloc((size_t)DIN_ * R_ * 2);
    u16*   xzb     = (u16*)alloc((size_t)NTOK * 2 * DIN_ * 2);    // 16MB bf16
    u16*   xcb     = (u16*)alloc((size_t)NTOK * DIN_ * 2);
    u16*   xdb     = (u16*)alloc((size_t)NTOK * 128 * 2);
    u16*   dtq     = (u16*)alloc((size_t)NTOK * DIN_ * 2);        // 8MB bf16
    u16*   yg      = (u16*)alloc((size_t)NTOK * DIN_ * 2);
    u16*   Pbuf    = (u16*)alloc((size_t)B_ * NCH * DIN_ * S_ * 2);   // 4MB
    u16*   Hbuf    = (u16*)alloc((size_t)B_ * NCH * DIN_ * S_ * 2);   // 4MB
    float* h0buf   = (float*)alloc((size_t)B_ * NCH * DIN_ * S_ * 4); // 8MB
    u16*   part_out = (u16*)alloc((size_t)4 * NTOK * D_ * 2);     // 16MB bf16
    // wx partials [16][2048][128] bf16 (8MB) alias part_out (disjoint lifetimes).
    u16*   part_wx  = part_out;

    // prep: rmsnorm (2048 blocks) + 4 transposes (6528 blocks)
    prep_kernel<<<NTOK + 6528, 256, 0, stream>>>(
        x, norm_w, xn, W_in, WinT, W_out, WoutT, W_x, WxT, W_dt, WdtT);

    // xz = xn @ W_in -> bf16 [2048, 4096]  (32x32 = 1024 blocks x 512thr; CX=8)
    gemm_bf16<64, 128, 8><<<dim3(2 * DIN_ / 128, NTOK / 64), 512, 0, stream>>>(
        xn, D_, WinT, D_, nullptr, xzb, 2 * DIN_, nullptr, NTOK, 2 * DIN_, D_, 0);
    // conv + silu -> xcb (bf16), 2 channels x 4 L-positions per thread
    conv_silu_kernel<<<(NTOK * DIN_ / 8) / 256, 256, 0, stream>>>(xzb, conv_w, conv_b, xcb);
    // xd = xc @ W_x (padded to N=128), split-K=16, bf16 partials (512 blocks)
    gemm_bf16<64, 128, 1><<<dim3(1, NTOK / 64, 16), 512, 0, stream>>>(
        xcb, DIN_, WxT, DIN_, nullptr, part_wx, 128, nullptr, NTOK, 128, DIN_ / 16, 3);
    reduce_wx_kernel<<<(NTOK * 128 / 4) / 256, 256, 0, stream>>>(part_wx, xdb);
    // dt = softplus(xd[:, :64] @ W_dt + b_dt) -> bf16  (16x32 = 512 blocks)
    gemm_bf16<64, 128, 8><<<dim3(DIN_ / 128, NTOK / 64), 512, 0, stream>>>(
        xdb, 128, WdtT, R_, nullptr, dtq, DIN_, b_dt, NTOK, DIN_, R_, 1);
    // chunked selective scan + gate -> yg (bf16), din-in-lane layout
    {
        dim3 grid(DIN_ / 256, NCH, B_);
        scan_chunk_kernel<<<grid, 256, 0, stream>>>(dtq, xcb, xdb, A_log, Pbuf, Hbuf);
        scan_combine_kernel<<<(B_ * DIN_ * S_) / 256, 256, 0, stream>>>(Pbuf, Hbuf, h0buf);
        scan_final_kernel<<<grid, 256, 0, stream>>>(dtq, xcb, xdb, A_log, h0buf, D_skip, xzb, yg);
    }
    // out = x + yg @ W_out, split-K=4, bf16 partials  (8x32x4 = 1024 blocks; CX=8)
    gemm_bf16<64, 128, 8><<<dim3(D_ / 128, NTOK / 64, 4), 512, 0, stream>>>(
        yg, DIN_, WoutT, DIN_, nullptr, part_out, D_, nullptr, NTOK, D_, DIN_ / 4, 3);
    reduce_out_kernel<<<(NTOK * D_ / 4) / 256, 256, 0, stream>>>(part_out, x, out);
}